// Round 10
// baseline (1155.533 us; speedup 1.0000x reference)
//
#include <hip/hip_runtime.h>
#include <cstdint>

typedef unsigned short u16;
typedef unsigned int u32;
typedef __attribute__((ext_vector_type(8))) short s8v;   // 8 bf16 (4 VGPRs)
typedef __attribute__((ext_vector_type(4))) float f4v;   // MFMA acc

#define FCH 256

__device__ __forceinline__ float bf2f(u16 u){ return __uint_as_float(((u32)u)<<16); }
__device__ __forceinline__ u16 f2bf(float x){
  u32 u = __float_as_uint(x);
  u += 0x7fffu + ((u>>16)&1u);
  return (u16)(u>>16);
}
__device__ __forceinline__ uint4 pack8(float4 a, float4 b){
  uint4 o;
  o.x = (u32)f2bf(a.x) | ((u32)f2bf(a.y)<<16);
  o.y = (u32)f2bf(a.z) | ((u32)f2bf(a.w)<<16);
  o.z = (u32)f2bf(b.x) | ((u32)f2bf(b.y)<<16);
  o.w = (u32)f2bf(b.z) | ((u32)f2bf(b.w)<<16);
  return o;
}
__device__ __forceinline__ float seluf(float x){
  const float sc = 1.0507009873554805f, al = 1.6732632423543772f;
  return x > 0.f ? sc*x : sc*al*(__expf(x)-1.f);
}

// ---------------------------------------------------------------------------
// Weight packing (fp32 -> bf16 fragments): lane l slot j of frag (kc,nt) =
// B[kc*32 + (l>>4)*8 + j][nt*16 + (l&15)]  (16B/lane contiguous)
// ---------------------------------------------------------------------------
__global__ __launch_bounds__(256) void pack_kernel(
    const float* __restrict__ Wc, const float* __restrict__ Wf, const float* __restrict__ Wg,
    const float* __restrict__ Wr, const float* __restrict__ Ws,
    const float* __restrict__ Wd1, const float* __restrict__ Wd2,
    u16* __restrict__ Bp1, u16* __restrict__ Bp2, u16* __restrict__ Bp0,
    u16* __restrict__ BpD1, u16* __restrict__ BpD2)
{
  int gid = blockIdx.x*256 + threadIdx.x;
  int frag = gid >> 6;
  int lane = gid & 63;
  int q = lane >> 4, i15 = lane & 15;
  u16 v[8];
  u16* dst;
  if (frag < 4096) {                       // Bp1: [Wf|Wg] K=512 (tap-major)
    int layer = frag >> 9, rem = frag & 511;
    int kc = rem >> 5, nt = rem & 31;
    int n = nt*16 + i15;
    const float* W = (n < 256) ? Wf : Wg;
    int nn = (n < 256) ? n : n - 256;
    #pragma unroll
    for (int j = 0; j < 8; ++j) {
      int k = kc*32 + q*8 + j;
      int tap = k >> 8, cin = k & 255;
      v[j] = f2bf(W[((size_t)((layer*2 + tap)*256 + cin))*256 + nn]);
    }
    dst = Bp1 + (size_t)frag*512 + lane*8;
  } else if (frag < 6144) {                // Bp2: [Wr|Ws] K=256
    int f = frag - 4096;
    int layer = f >> 8, rem = f & 255;
    int kc = rem >> 5, nt = rem & 31;
    int n = nt*16 + i15;
    const float* W = (n < 256) ? Wr : Ws;
    int nn = (n < 256) ? n : n - 256;
    #pragma unroll
    for (int j = 0; j < 8; ++j) {
      int k = kc*32 + q*8 + j;
      v[j] = f2bf(W[((size_t)(layer*256 + k))*256 + nn]);
    }
    dst = Bp2 + (size_t)f*512 + lane*8;
  } else if (frag < 6208) {                // Bp0: Wc K=128
    int f = frag - 6144;
    int kc = f >> 4, nt = f & 15;
    int n = nt*16 + i15;
    #pragma unroll
    for (int j = 0; j < 8; ++j) {
      int k = kc*32 + q*8 + j;
      int tap = k >> 6, cin = k & 63;
      v[j] = f2bf(Wc[(size_t)(tap*64 + cin)*256 + n]);
    }
    dst = Bp0 + (size_t)f*512 + lane*8;
  } else if (frag < 6240) {                // BpD1: Wd1 [256,64]
    int f = frag - 6208;
    int kc = f >> 2, nt = f & 3;
    int n = nt*16 + i15;
    #pragma unroll
    for (int j = 0; j < 8; ++j) {
      int k = kc*32 + q*8 + j;
      v[j] = f2bf(Wd1[(size_t)k*64 + n]);
    }
    dst = BpD1 + (size_t)f*512 + lane*8;
  } else if (frag < 6248) {                // BpD2: Wd2 [64,64]
    int f = frag - 6240;
    int kc = f >> 2, nt = f & 3;
    int n = nt*16 + i15;
    #pragma unroll
    for (int j = 0; j < 8; ++j) {
      int k = kc*32 + q*8 + j;
      v[j] = f2bf(Wd2[(size_t)k*64 + n]);
    }
    dst = BpD2 + (size_t)f*512 + lane*8;
  } else return;
  uint4 o;
  o.x = (u32)v[0] | ((u32)v[1] << 16);
  o.y = (u32)v[2] | ((u32)v[3] << 16);
  o.z = (u32)v[4] | ((u32)v[5] << 16);
  o.w = (u32)v[6] | ((u32)v[7] << 16);
  *reinterpret_cast<uint4*>(dst) = o;
}

// ---------------------------------------------------------------------------
// Initial causal conv (dilation 1, no bias): out0 = [x[t-1]|x[t]] @ cat(Wc)
// ---------------------------------------------------------------------------
__global__ __launch_bounds__(256, 2) void conv0_kernel(
    const float* __restrict__ x, u16* __restrict__ outBf,
    const u16* __restrict__ Bp0)
{
  __shared__ __align__(16) u16 ldsA[2][2048];
  const int tid = threadIdx.x;
  const int w = tid >> 6, lane = tid & 63, q = lane >> 4, i15 = lane & 15;
  const int rb = blockIdx.x * 64;
  const int sm = tid >> 2, sg = tid & 3;
  const int grow = rb + sm;
  const int tpos = grow & 4095;
  const int sunit = ((sm >> 4)*64 + sg*16 + ((sm & 15) ^ (sg << 1))) * 8;
  const int runit = (q*16 + (i15 ^ (q << 1))) * 8;

  f4v acc[4][4];
  #pragma unroll
  for (int jj = 0; jj < 4; ++jj)
    #pragma unroll
    for (int mt = 0; mt < 4; ++mt)
      acc[jj][mt] = (f4v){0.f,0.f,0.f,0.f};

  float4 f0 = {0.f,0.f,0.f,0.f}, f1 = {0.f,0.f,0.f,0.f};
  if (tpos >= 1) {
    const float* px = x + (size_t)(grow-1)*64 + sg*8;
    f0 = *reinterpret_cast<const float4*>(px);
    f1 = *reinterpret_cast<const float4*>(px + 4);
  }
  *reinterpret_cast<uint4*>(&ldsA[0][sunit]) = pack8(f0, f1);
  s8v bcur[4], bnxt[4];
  #pragma unroll
  for (int jj = 0; jj < 4; ++jj)
    bcur[jj] = *reinterpret_cast<const s8v*>(Bp0 + ((size_t)(w + 4*jj)*64 + lane)*8);
  __syncthreads();

  for (int kc = 0; kc < 4; ++kc) {
    const int cur = kc & 1;
    uint4 an = {0u,0u,0u,0u};
    if (kc < 3) {
      int kg = (kc+1)*32 + sg*8;
      int tap = kg >> 6, col = kg & 63;
      float4 g0 = {0.f,0.f,0.f,0.f}, g1 = {0.f,0.f,0.f,0.f};
      if (tap) {
        const float* px = x + (size_t)grow*64 + col;
        g0 = *reinterpret_cast<const float4*>(px);
        g1 = *reinterpret_cast<const float4*>(px + 4);
      } else if (tpos >= 1) {
        const float* px = x + (size_t)(grow-1)*64 + col;
        g0 = *reinterpret_cast<const float4*>(px);
        g1 = *reinterpret_cast<const float4*>(px + 4);
      }
      an = pack8(g0, g1);
      #pragma unroll
      for (int jj = 0; jj < 4; ++jj)
        bnxt[jj] = *reinterpret_cast<const s8v*>(Bp0 + (((size_t)(kc+1)*16 + (w + 4*jj))*64 + lane)*8);
    }
    s8v af[4];
    #pragma unroll
    for (int mt = 0; mt < 4; ++mt)
      af[mt] = *reinterpret_cast<const s8v*>(&ldsA[cur][mt*512 + runit]);
    #pragma unroll
    for (int jj = 0; jj < 4; ++jj)
      #pragma unroll
      for (int mt = 0; mt < 4; ++mt)
        acc[jj][mt] = __builtin_amdgcn_mfma_f32_16x16x32_bf16(af[mt], bcur[jj], acc[jj][mt], 0,0,0);
    if (kc < 3) {
      *reinterpret_cast<uint4*>(&ldsA[cur ^ 1][sunit]) = an;
      #pragma unroll
      for (int jj = 0; jj < 4; ++jj) bcur[jj] = bnxt[jj];
    }
    __syncthreads();
  }

  #pragma unroll
  for (int jj = 0; jj < 4; ++jj) {
    const int cc = (w + 4*jj)*16 + i15;
    #pragma unroll
    for (int mt = 0; mt < 4; ++mt)
      #pragma unroll
      for (int r = 0; r < 4; ++r) {
        const int g2 = rb + mt*16 + q*4 + r;
        outBf[(size_t)g2*FCH + cc] = f2bf(acc[jj][mt][r]);
      }
  }
}

// ---------------------------------------------------------------------------
// One WaveNet residual layer, fused, barrier-minimal (5 barriers/layer).
// M=64 rows/block, N=512. A staged per-tap as a full 64x256 LDS tile
// (XOR-swizzled units, stride 256 -> 2-way max conflicts), K-chunks run
// barrier-free with register B-prefetch. ldsU is reused for Z before stage 2.
// XCD swizzle: tile = (bid&7)*nT8 + (bid>>3) keeps each XCD's rows contiguous.
// ---------------------------------------------------------------------------
__global__ __launch_bounds__(256, 3) void layer_kernel(
    const u16* __restrict__ inBf, u16* __restrict__ outBf,
    u16* __restrict__ skipB,
    const u16* __restrict__ Bp1, const u16* __restrict__ Bp2,
    const float* __restrict__ br, const float* __restrict__ bs,
    int dil, int first, int nT8)
{
  __shared__ __align__(16) u16 ldsU[64*256];   // 32 KB (A per tap, then Z)
  const int tid = threadIdx.x;
  const int w = tid >> 6, lane = tid & 63, q = lane >> 4, i15 = lane & 15;
  const int bid = blockIdx.x;
  const int tile = nT8 ? ((bid & 7) * nT8 + (bid >> 3)) : bid;
  const int rb = tile * 64;

  f4v acc[8][4];
  #pragma unroll
  for (int jj = 0; jj < 8; ++jj)
    #pragma unroll
    for (int mt = 0; mt < 4; ++mt)
      acc[jj][mt] = (f4v){0.f,0.f,0.f,0.f};

  // preload stage1 B chunk 0
  s8v bcur[8], bnxt[8];
  #pragma unroll
  for (int jj = 0; jj < 8; ++jj)
    bcur[jj] = *reinterpret_cast<const s8v*>(Bp1 + ((size_t)(w + 4*jj)*64 + lane)*8);

  // ---- phase A: tap0 rows (t-dil, causal-zero) -> ldsU ----
  #pragma unroll
  for (int u = 0; u < 8; ++u) {
    int f = tid + 256*u;
    int row = f >> 5, unit = f & 31;
    int g = rb + row;
    uint4 v = {0u,0u,0u,0u};
    if ((g & 4095) >= dil)
      v = *reinterpret_cast<const uint4*>(inBf + (size_t)(g - dil)*FCH + unit*8);
    *reinterpret_cast<uint4*>(&ldsU[row*256 + (unit ^ (row & 7))*8]) = v;
  }
  __syncthreads();

  // ---- stage1 chunks 0..7 (tap0), barrier-free ----
  for (int kc = 0; kc < 8; ++kc) {
    #pragma unroll
    for (int jj = 0; jj < 8; ++jj)
      bnxt[jj] = *reinterpret_cast<const s8v*>(Bp1 + (((size_t)(kc+1)*32 + (w + 4*jj))*64 + lane)*8);
    s8v af[4];
    #pragma unroll
    for (int mt = 0; mt < 4; ++mt)
      af[mt] = *reinterpret_cast<const s8v*>(&ldsU[(mt*16 + i15)*256 + ((kc*4 + q) ^ (i15 & 7))*8]);
    #pragma unroll
    for (int jj = 0; jj < 8; ++jj)
      #pragma unroll
      for (int mt = 0; mt < 4; ++mt)
        acc[jj][mt] = __builtin_amdgcn_mfma_f32_16x16x32_bf16(af[mt], bcur[jj], acc[jj][mt], 0,0,0);
    #pragma unroll
    for (int jj = 0; jj < 8; ++jj) bcur[jj] = bnxt[jj];
  }
  __syncthreads();   // all waves done reading tap0 tile

  // ---- phase B: tap1 rows (t) -> ldsU ----
  #pragma unroll
  for (int u = 0; u < 8; ++u) {
    int f = tid + 256*u;
    int row = f >> 5, unit = f & 31;
    int g = rb + row;
    uint4 v = *reinterpret_cast<const uint4*>(inBf + (size_t)g*FCH + unit*8);
    *reinterpret_cast<uint4*>(&ldsU[row*256 + (unit ^ (row & 7))*8]) = v;
  }
  __syncthreads();

  // ---- stage1 chunks 8..15 (tap1), barrier-free ----
  for (int kc = 8; kc < 16; ++kc) {
    if (kc < 15) {
      #pragma unroll
      for (int jj = 0; jj < 8; ++jj)
        bnxt[jj] = *reinterpret_cast<const s8v*>(Bp1 + (((size_t)(kc+1)*32 + (w + 4*jj))*64 + lane)*8);
    }
    s8v af[4];
    #pragma unroll
    for (int mt = 0; mt < 4; ++mt)
      af[mt] = *reinterpret_cast<const s8v*>(&ldsU[(mt*16 + i15)*256 + (((kc & 7)*4 + q) ^ (i15 & 7))*8]);
    #pragma unroll
    for (int jj = 0; jj < 8; ++jj)
      #pragma unroll
      for (int mt = 0; mt < 4; ++mt)
        acc[jj][mt] = __builtin_amdgcn_mfma_f32_16x16x32_bf16(af[mt], bcur[jj], acc[jj][mt], 0,0,0);
    if (kc < 15) {
      #pragma unroll
      for (int jj = 0; jj < 8; ++jj) bcur[jj] = bnxt[jj];
    }
  }
  __syncthreads();   // before Z overwrites ldsU

  // preload stage2 B chunk 0 (latency hidden behind activation VALU)
  s8v b2c[8], b2n[8];
  #pragma unroll
  for (int jj = 0; jj < 8; ++jj)
    b2c[jj] = *reinterpret_cast<const s8v*>(Bp2 + ((size_t)(w + 4*jj)*64 + lane)*8);

  // ---- activation: Z = tanh(F)*sigmoid(G) -> ldsU (XOR-swizzled) ----
  #pragma unroll
  for (int jj = 0; jj < 4; ++jj) {
    const int colb = (w + 4*jj)*16 + i15;
    const int unit = colb >> 3, rem = colb & 7;
    #pragma unroll
    for (int mt = 0; mt < 4; ++mt)
      #pragma unroll
      for (int r = 0; r < 4; ++r) {
        float f = acc[jj][mt][r];
        float g = acc[jj+4][mt][r];
        float z = (1.f - 2.f/(__expf(2.f*f) + 1.f)) * (1.f/(1.f + __expf(-g)));
        int mrow = mt*16 + q*4 + r;
        ldsU[mrow*256 + (unit ^ (mrow & 7))*8 + rem] = f2bf(z);
      }
  }
  __syncthreads();

  // ---- init stage2 acc: residual (bf16) / skip / bias ----
  #pragma unroll
  for (int jj = 0; jj < 8; ++jj) {
    const int nt = w + 4*jj;
    const bool isR = (jj < 4);
    const int cc = (isR ? nt*16 : (nt-16)*16) + i15;
    const float bias = isR ? br[cc] : bs[cc];
    #pragma unroll
    for (int mt = 0; mt < 4; ++mt)
      #pragma unroll
      for (int r = 0; r < 4; ++r) {
        const int g2 = rb + mt*16 + q*4 + r;
        float vv;
        if (isR) vv = bf2f(inBf[(size_t)g2*FCH + cc]) + bias;
        else     vv = first ? bias : (bf2f(skipB[(size_t)g2*FCH + cc]) + bias);
        acc[jj][mt][r] = vv;
      }
  }

  // ---- stage2 chunks 0..7, barrier-free ----
  for (int kc = 0; kc < 8; ++kc) {
    if (kc < 7) {
      #pragma unroll
      for (int jj = 0; jj < 8; ++jj)
        b2n[jj] = *reinterpret_cast<const s8v*>(Bp2 + (((size_t)(kc+1)*32 + (w + 4*jj))*64 + lane)*8);
    }
    s8v af[4];
    #pragma unroll
    for (int mt = 0; mt < 4; ++mt)
      af[mt] = *reinterpret_cast<const s8v*>(&ldsU[(mt*16 + i15)*256 + ((kc*4 + q) ^ (i15 & 7))*8]);
    #pragma unroll
    for (int jj = 0; jj < 8; ++jj)
      #pragma unroll
      for (int mt = 0; mt < 4; ++mt)
        acc[jj][mt] = __builtin_amdgcn_mfma_f32_16x16x32_bf16(af[mt], b2c[jj], acc[jj][mt], 0,0,0);
    if (kc < 7) {
      #pragma unroll
      for (int jj = 0; jj < 8; ++jj) b2c[jj] = b2n[jj];
    }
  }

  // ---- epilogue ----
  #pragma unroll
  for (int jj = 0; jj < 8; ++jj) {
    const int nt = w + 4*jj;
    const bool isR = (jj < 4);
    const int cc = (isR ? nt*16 : (nt-16)*16) + i15;
    #pragma unroll
    for (int mt = 0; mt < 4; ++mt)
      #pragma unroll
      for (int r = 0; r < 4; ++r) {
        const int g2 = rb + mt*16 + q*4 + r;
        u16 hv = f2bf(acc[jj][mt][r]);
        if (isR) outBf[(size_t)g2*FCH + cc] = hv;
        else     skipB[(size_t)g2*FCH + cc] = hv;
      }
  }
}

// ---------------------------------------------------------------------------
// Final head: h=selu(skip); h=selu(h@Wd1+bd1); out=h@Wd2+bd2  -- OUT IS FP32
// ---------------------------------------------------------------------------
__global__ __launch_bounds__(256, 2) void final_kernel(
    const u16* __restrict__ skipB, const u16* __restrict__ BpD1, const u16* __restrict__ BpD2,
    const float* __restrict__ bd1, const float* __restrict__ bd2, float* __restrict__ outp)
{
  __shared__ __align__(16) u16 ldsH[64*264];
  __shared__ __align__(16) u16 ldsH2[64*72];
  const int tid = threadIdx.x;
  const int w = tid >> 6, lane = tid & 63, q = lane >> 4, i15 = lane & 15;
  const int rb = blockIdx.x * 64;
  const int sm = tid >> 2, sseg = tid & 3;

  {
    const u16* sp = skipB + (size_t)(rb + sm)*256 + sseg*64;
    u16* dr = &ldsH[sm*264 + sseg*64];
    #pragma unroll
    for (int u = 0; u < 8; ++u) {
      uint4 raw = *reinterpret_cast<const uint4*>(sp + u*8);
      u32 rr[4] = {raw.x, raw.y, raw.z, raw.w};
      uint4 o;
      u32 oo[4];
      #pragma unroll
      for (int p = 0; p < 4; ++p) {
        float e0 = seluf(bf2f((u16)(rr[p] & 0xffffu)));
        float e1 = seluf(bf2f((u16)(rr[p] >> 16)));
        oo[p] = (u32)f2bf(e0) | ((u32)f2bf(e1) << 16);
      }
      o.x = oo[0]; o.y = oo[1]; o.z = oo[2]; o.w = oo[3];
      *reinterpret_cast<uint4*>(dr + u*8) = o;
    }
  }
  __syncthreads();

  f4v a1[4];
  #pragma unroll
  for (int mt = 0; mt < 4; ++mt) a1[mt] = (f4v){0.f,0.f,0.f,0.f};
  for (int kc = 0; kc < 8; ++kc) {
    s8v b = *reinterpret_cast<const s8v*>(BpD1 + ((size_t)(kc*4 + w)*64 + lane)*8);
    #pragma unroll
    for (int mt = 0; mt < 4; ++mt) {
      s8v af = *reinterpret_cast<const s8v*>(&ldsH[(mt*16 + i15)*264 + kc*32 + q*8]);
      a1[mt] = __builtin_amdgcn_mfma_f32_16x16x32_bf16(af, b, a1[mt], 0,0,0);
    }
  }
  const float bb1 = bd1[w*16 + i15];
  #pragma unroll
  for (int mt = 0; mt < 4; ++mt)
    #pragma unroll
    for (int r = 0; r < 4; ++r)
      ldsH2[(mt*16 + q*4 + r)*72 + w*16 + i15] = f2bf(seluf(a1[mt][r] + bb1));
  __syncthreads();

  f4v a2[4];
  #pragma unroll
  for (int mt = 0; mt < 4; ++mt) a2[mt] = (f4v){0.f,0.f,0.f,0.f};
  #pragma unroll
  for (int kc = 0; kc < 2; ++kc) {
    s8v b = *reinterpret_cast<const s8v*>(BpD2 + ((size_t)(kc*4 + w)*64 + lane)*8);
    #pragma unroll
    for (int mt = 0; mt < 4; ++mt) {
      s8v af = *reinterpret_cast<const s8v*>(&ldsH2[(mt*16 + i15)*72 + kc*32 + q*8]);
      a2[mt] = __builtin_amdgcn_mfma_f32_16x16x32_bf16(af, b, a2[mt], 0,0,0);
    }
  }
  const float bb2 = bd2[w*16 + i15];
  #pragma unroll
  for (int mt = 0; mt < 4; ++mt)
    #pragma unroll
    for (int r = 0; r < 4; ++r)
      outp[(size_t)(rb + mt*16 + q*4 + r)*64 + w*16 + i15] = a2[mt][r] + bb2;  // FP32
}

// Diagnostic sentinel (should never fire; ws proven >= 84 MB).
__global__ __launch_bounds__(256) void zero_kernel(uint4* __restrict__ outp, int n16)
{
  int i = blockIdx.x*256 + threadIdx.x;
  if (i < n16) outp[i] = (uint4){0u,0u,0u,0u};
}

// ---------------------------------------------------------------------------
extern "C" void kernel_launch(void* const* d_in, const int* in_sizes, int n_in,
                              void* d_out, int out_size, void* d_ws, size_t ws_size,
                              hipStream_t stream)
{
  (void)n_in;
  const float* x   = (const float*)d_in[0];
  const float* Wc  = (const float*)d_in[1];
  const float* Wf  = (const float*)d_in[2];
  const float* Wg  = (const float*)d_in[3];
  const float* Wr  = (const float*)d_in[4];
  const float* br  = (const float*)d_in[5];
  const float* Ws  = (const float*)d_in[6];
  const float* bs  = (const float*)d_in[7];
  const float* Wd1 = (const float*)d_in[8];
  const float* bd1 = (const float*)d_in[9];
  const float* Wd2 = (const float*)d_in[10];
  const float* bd2 = (const float*)d_in[11];

  const size_t ROWS = (size_t)in_sizes[0] / 64;     // B*T = 32768
  const int gridC = (int)(ROWS / 64);               // 512 (conv0/final/layers)
  const int nTiles = gridC;
  const int nT8 = (nTiles % 8 == 0) ? nTiles / 8 : 0;   // XCD swizzle factor

  const size_t packsB = (size_t)6248 * 512 * 2;     // 6.4 MB
  const size_t bfBuf  = ROWS * 256 * 2;             // 16.78 MB
  const size_t needB = packsB + 3*bfBuf;            // 56.7 MB

  if (ws_size < needB) {
    int n16 = (out_size * 4) / 16;                  // fp32 out
    zero_kernel<<<(n16 + 255)/256, 256, 0, stream>>>((uint4*)d_out, n16);
    return;
  }

  char* ws = (char*)d_ws;
  u16* Bp1    = (u16*)ws;            ws += (size_t)4096*512*2;
  u16* Bp2    = (u16*)ws;            ws += (size_t)2048*512*2;
  u16* Bp0    = (u16*)ws;            ws += (size_t)64*512*2;
  u16* BpD1   = (u16*)ws;            ws += (size_t)32*512*2;
  u16* BpD2   = (u16*)ws;            ws += (size_t)8*512*2;
  u16* skipB  = (u16*)ws;            ws += bfBuf;
  u16* bufA   = (u16*)ws;            ws += bfBuf;
  u16* bufB   = (u16*)ws;            ws += bfBuf;

  pack_kernel<<<1562, 256, 0, stream>>>(Wc, Wf, Wg, Wr, Ws, Wd1, Wd2,
                                        Bp1, Bp2, Bp0, BpD1, BpD2);
  conv0_kernel<<<gridC, 256, 0, stream>>>(x, bufA, Bp0);
  u16* bufs[2] = {bufA, bufB};
  for (int i = 0; i < 8; ++i) {
    layer_kernel<<<nTiles, 256, 0, stream>>>(
        bufs[i & 1], bufs[(i + 1) & 1], skipB,
        Bp1 + (size_t)i*262144, Bp2 + (size_t)i*131072,
        br + i*256, bs + i*256, 2 << i, (i == 0) ? 1 : 0, nT8);
  }
  final_kernel<<<gridC, 256, 0, stream>>>(skipB, BpD1, BpD2, bd1, bd2, (float*)d_out);
}

// Round 11
// 848.486 us; speedup vs baseline: 1.3619x; 1.3619x over previous
//
#include <hip/hip_runtime.h>
#include <cstdint>

typedef unsigned short u16;
typedef unsigned int u32;
typedef __attribute__((ext_vector_type(8))) short s8v;   // 8 bf16 (4 VGPRs)
typedef __attribute__((ext_vector_type(4))) float f4v;   // MFMA acc

#define FCH 256

__device__ __forceinline__ float bf2f(u16 u){ return __uint_as_float(((u32)u)<<16); }
__device__ __forceinline__ u16 f2bf(float x){
  u32 u = __float_as_uint(x);
  u += 0x7fffu + ((u>>16)&1u);
  return (u16)(u>>16);
}
__device__ __forceinline__ uint4 pack8(float4 a, float4 b){
  uint4 o;
  o.x = (u32)f2bf(a.x) | ((u32)f2bf(a.y)<<16);
  o.y = (u32)f2bf(a.z) | ((u32)f2bf(a.w)<<16);
  o.z = (u32)f2bf(b.x) | ((u32)f2bf(b.y)<<16);
  o.w = (u32)f2bf(b.z) | ((u32)f2bf(b.w)<<16);
  return o;
}
__device__ __forceinline__ float seluf(float x){
  const float sc = 1.0507009873554805f, al = 1.6732632423543772f;
  return x > 0.f ? sc*x : sc*al*(__expf(x)-1.f);
}

// ---------------------------------------------------------------------------
// Weight packing (fp32 -> bf16 fragments): lane l slot j of frag (kc,nt) =
// B[kc*32 + (l>>4)*8 + j][nt*16 + (l&15)]  (16B/lane contiguous)
// ---------------------------------------------------------------------------
__global__ __launch_bounds__(256) void pack_kernel(
    const float* __restrict__ Wc, const float* __restrict__ Wf, const float* __restrict__ Wg,
    const float* __restrict__ Wr, const float* __restrict__ Ws,
    const float* __restrict__ Wd1, const float* __restrict__ Wd2,
    u16* __restrict__ Bp1, u16* __restrict__ Bp2, u16* __restrict__ Bp0,
    u16* __restrict__ BpD1, u16* __restrict__ BpD2)
{
  int gid = blockIdx.x*256 + threadIdx.x;
  int frag = gid >> 6;
  int lane = gid & 63;
  int q = lane >> 4, i15 = lane & 15;
  u16 v[8];
  u16* dst;
  if (frag < 4096) {                       // Bp1: [Wf|Wg] K=512 (tap-major)
    int layer = frag >> 9, rem = frag & 511;
    int kc = rem >> 5, nt = rem & 31;
    int n = nt*16 + i15;
    const float* W = (n < 256) ? Wf : Wg;
    int nn = (n < 256) ? n : n - 256;
    #pragma unroll
    for (int j = 0; j < 8; ++j) {
      int k = kc*32 + q*8 + j;
      int tap = k >> 8, cin = k & 255;
      v[j] = f2bf(W[((size_t)((layer*2 + tap)*256 + cin))*256 + nn]);
    }
    dst = Bp1 + (size_t)frag*512 + lane*8;
  } else if (frag < 6144) {                // Bp2: [Wr|Ws] K=256
    int f = frag - 4096;
    int layer = f >> 8, rem = f & 255;
    int kc = rem >> 5, nt = rem & 31;
    int n = nt*16 + i15;
    const float* W = (n < 256) ? Wr : Ws;
    int nn = (n < 256) ? n : n - 256;
    #pragma unroll
    for (int j = 0; j < 8; ++j) {
      int k = kc*32 + q*8 + j;
      v[j] = f2bf(W[((size_t)(layer*256 + k))*256 + nn]);
    }
    dst = Bp2 + (size_t)f*512 + lane*8;
  } else if (frag < 6208) {                // Bp0: Wc K=128
    int f = frag - 6144;
    int kc = f >> 4, nt = f & 15;
    int n = nt*16 + i15;
    #pragma unroll
    for (int j = 0; j < 8; ++j) {
      int k = kc*32 + q*8 + j;
      int tap = k >> 6, cin = k & 63;
      v[j] = f2bf(Wc[(size_t)(tap*64 + cin)*256 + n]);
    }
    dst = Bp0 + (size_t)f*512 + lane*8;
  } else if (frag < 6240) {                // BpD1: Wd1 [256,64]
    int f = frag - 6208;
    int kc = f >> 2, nt = f & 3;
    int n = nt*16 + i15;
    #pragma unroll
    for (int j = 0; j < 8; ++j) {
      int k = kc*32 + q*8 + j;
      v[j] = f2bf(Wd1[(size_t)k*64 + n]);
    }
    dst = BpD1 + (size_t)f*512 + lane*8;
  } else if (frag < 6248) {                // BpD2: Wd2 [64,64]
    int f = frag - 6240;
    int kc = f >> 2, nt = f & 3;
    int n = nt*16 + i15;
    #pragma unroll
    for (int j = 0; j < 8; ++j) {
      int k = kc*32 + q*8 + j;
      v[j] = f2bf(Wd2[(size_t)k*64 + n]);
    }
    dst = BpD2 + (size_t)f*512 + lane*8;
  } else return;
  uint4 o;
  o.x = (u32)v[0] | ((u32)v[1] << 16);
  o.y = (u32)v[2] | ((u32)v[3] << 16);
  o.z = (u32)v[4] | ((u32)v[5] << 16);
  o.w = (u32)v[6] | ((u32)v[7] << 16);
  *reinterpret_cast<uint4*>(dst) = o;
}

// ---------------------------------------------------------------------------
// Initial causal conv (dilation 1, no bias): out0 = [x[t-1]|x[t]] @ cat(Wc)
// ---------------------------------------------------------------------------
__global__ __launch_bounds__(256, 2) void conv0_kernel(
    const float* __restrict__ x, u16* __restrict__ outBf,
    const u16* __restrict__ Bp0)
{
  __shared__ __align__(16) u16 ldsA[2][2048];
  const int tid = threadIdx.x;
  const int w = tid >> 6, lane = tid & 63, q = lane >> 4, i15 = lane & 15;
  const int rb = blockIdx.x * 64;
  const int sm = tid >> 2, sg = tid & 3;
  const int grow = rb + sm;
  const int tpos = grow & 4095;
  const int sunit = ((sm >> 4)*64 + sg*16 + ((sm & 15) ^ (sg << 1))) * 8;
  const int runit = (q*16 + (i15 ^ (q << 1))) * 8;

  f4v acc[4][4];
  #pragma unroll
  for (int jj = 0; jj < 4; ++jj)
    #pragma unroll
    for (int mt = 0; mt < 4; ++mt)
      acc[jj][mt] = (f4v){0.f,0.f,0.f,0.f};

  float4 f0 = {0.f,0.f,0.f,0.f}, f1 = {0.f,0.f,0.f,0.f};
  if (tpos >= 1) {
    const float* px = x + (size_t)(grow-1)*64 + sg*8;
    f0 = *reinterpret_cast<const float4*>(px);
    f1 = *reinterpret_cast<const float4*>(px + 4);
  }
  *reinterpret_cast<uint4*>(&ldsA[0][sunit]) = pack8(f0, f1);
  s8v bcur[4], bnxt[4];
  #pragma unroll
  for (int jj = 0; jj < 4; ++jj)
    bcur[jj] = *reinterpret_cast<const s8v*>(Bp0 + ((size_t)(w + 4*jj)*64 + lane)*8);
  __syncthreads();

  for (int kc = 0; kc < 4; ++kc) {
    const int cur = kc & 1;
    uint4 an = {0u,0u,0u,0u};
    if (kc < 3) {
      int kg = (kc+1)*32 + sg*8;
      int tap = kg >> 6, col = kg & 63;
      float4 g0 = {0.f,0.f,0.f,0.f}, g1 = {0.f,0.f,0.f,0.f};
      if (tap) {
        const float* px = x + (size_t)grow*64 + col;
        g0 = *reinterpret_cast<const float4*>(px);
        g1 = *reinterpret_cast<const float4*>(px + 4);
      } else if (tpos >= 1) {
        const float* px = x + (size_t)(grow-1)*64 + col;
        g0 = *reinterpret_cast<const float4*>(px);
        g1 = *reinterpret_cast<const float4*>(px + 4);
      }
      an = pack8(g0, g1);
      #pragma unroll
      for (int jj = 0; jj < 4; ++jj)
        bnxt[jj] = *reinterpret_cast<const s8v*>(Bp0 + (((size_t)(kc+1)*16 + (w + 4*jj))*64 + lane)*8);
    }
    s8v af[4];
    #pragma unroll
    for (int mt = 0; mt < 4; ++mt)
      af[mt] = *reinterpret_cast<const s8v*>(&ldsA[cur][mt*512 + runit]);
    #pragma unroll
    for (int jj = 0; jj < 4; ++jj)
      #pragma unroll
      for (int mt = 0; mt < 4; ++mt)
        acc[jj][mt] = __builtin_amdgcn_mfma_f32_16x16x32_bf16(af[mt], bcur[jj], acc[jj][mt], 0,0,0);
    if (kc < 3) {
      *reinterpret_cast<uint4*>(&ldsA[cur ^ 1][sunit]) = an;
      #pragma unroll
      for (int jj = 0; jj < 4; ++jj) bcur[jj] = bnxt[jj];
    }
    __syncthreads();
  }

  #pragma unroll
  for (int jj = 0; jj < 4; ++jj) {
    const int cc = (w + 4*jj)*16 + i15;
    #pragma unroll
    for (int mt = 0; mt < 4; ++mt)
      #pragma unroll
      for (int r = 0; r < 4; ++r) {
        const int g2 = rb + mt*16 + q*4 + r;
        outBf[(size_t)g2*FCH + cc] = f2bf(acc[jj][mt][r]);
      }
  }
}

// ---------------------------------------------------------------------------
// One WaveNet residual layer — barrier-free K-loops, 1 __syncthreads/layer.
// M=32/block (1024 blocks), 4 waves, wave N=128 (8 nt tiles).
// A-fragments are loaded per-lane DIRECTLY from global (16 rows x 64B lines,
// fully consumed) — no LDS staging, no barrier drain; [kc&1] register
// double-buffering lets the compiler emit fine-grained vmcnt.
// jj<4 -> F/R tile nt=w*4+jj ; jj>=4 -> G/S tile nt=16+w*4+(jj-4).
// ---------------------------------------------------------------------------
__global__ __launch_bounds__(256, 3) void layer_kernel(
    const u16* __restrict__ inBf, u16* __restrict__ outBf,
    u16* __restrict__ skipB,
    const u16* __restrict__ Bp1, const u16* __restrict__ Bp2,
    const float* __restrict__ br, const float* __restrict__ bs,
    int dil, int first)
{
  __shared__ __align__(16) u16 ldsZ[32*264];   // 16.9 KB, Z transpose only
  const int tid = threadIdx.x;
  const int w = tid >> 6, lane = tid & 63, q = lane >> 4, i15 = lane & 15;
  const int rb = blockIdx.x * 32;

  f4v acc[8][2];
  #pragma unroll
  for (int jj = 0; jj < 8; ++jj)
    #pragma unroll
    for (int mt = 0; mt < 2; ++mt)
      acc[jj][mt] = (f4v){0.f,0.f,0.f,0.f};

  // per-lane A row indices for the two 16-row tiles
  const int gr[2] = { rb + i15, rb + 16 + i15 };
  const bool ok0[2] = { (gr[0] & 4095) >= dil, (gr[1] & 4095) >= dil };
  const u16* a0[2] = { inBf + (size_t)(gr[0] - dil)*FCH,   // tap0 (guarded)
                       inBf + (size_t)(gr[1] - dil)*FCH };
  const u16* a1[2] = { inBf + (size_t)gr[0]*FCH,           // tap1
                       inBf + (size_t)gr[1]*FCH };
  const int colq = q*8;

  // ---------------- stage 1: F|G, K=512, zero barriers ----------------
  {
    s8v bbuf[2][8];
    uint4 abuf[2][2];
    #pragma unroll
    for (int jj = 0; jj < 8; ++jj) {
      int nt = (jj < 4) ? (w*4 + jj) : (16 + w*4 + (jj - 4));
      bbuf[0][jj] = *reinterpret_cast<const s8v*>(Bp1 + ((size_t)nt*64 + lane)*8);
    }
    #pragma unroll
    for (int mt = 0; mt < 2; ++mt) {
      uint4 v = {0u,0u,0u,0u};
      if (ok0[mt]) v = *reinterpret_cast<const uint4*>(a0[mt] + colq);
      abuf[0][mt] = v;
    }
    for (int kc = 0; kc < 16; ++kc) {
      const int cur = kc & 1;
      if (kc < 15) {
        const int kn = kc + 1;
        #pragma unroll
        for (int jj = 0; jj < 8; ++jj) {
          int nt = (jj < 4) ? (w*4 + jj) : (16 + w*4 + (jj - 4));
          bbuf[cur ^ 1][jj] = *reinterpret_cast<const s8v*>(
              Bp1 + (((size_t)kn*32 + nt)*64 + lane)*8);
        }
        const int tap = kn >> 3, col = (kn & 7)*32 + colq;
        #pragma unroll
        for (int mt = 0; mt < 2; ++mt) {
          uint4 v = {0u,0u,0u,0u};
          if (tap) v = *reinterpret_cast<const uint4*>(a1[mt] + col);
          else if (ok0[mt]) v = *reinterpret_cast<const uint4*>(a0[mt] + col);
          abuf[cur ^ 1][mt] = v;
        }
      }
      #pragma unroll
      for (int jj = 0; jj < 8; ++jj)
        #pragma unroll
        for (int mt = 0; mt < 2; ++mt)
          acc[jj][mt] = __builtin_amdgcn_mfma_f32_16x16x32_bf16(
              *reinterpret_cast<const s8v*>(&abuf[cur][mt]), bbuf[cur][jj],
              acc[jj][mt], 0,0,0);
    }
  }

  // ---------------- activation: Z = tanh(F)*sigmoid(G) -> LDS ----------------
  #pragma unroll
  for (int jj = 0; jj < 4; ++jj) {
    const int colb = (w*4 + jj)*16 + i15;
    #pragma unroll
    for (int mt = 0; mt < 2; ++mt)
      #pragma unroll
      for (int r = 0; r < 4; ++r) {
        float f = acc[jj][mt][r];
        float g = acc[jj+4][mt][r];
        float z = (1.f - 2.f/(__expf(2.f*f) + 1.f)) * (1.f/(1.f + __expf(-g)));
        ldsZ[(mt*16 + q*4 + r)*264 + colb] = f2bf(z);
      }
  }

  // ---------------- init stage2 acc: residual (bf16) / skip / bias ----------------
  #pragma unroll
  for (int jj = 0; jj < 8; ++jj) {
    const bool isR = (jj < 4);
    const int cc = (isR ? (w*4 + jj) : (w*4 + jj - 4))*16 + i15;
    const float bias = isR ? br[cc] : bs[cc];
    #pragma unroll
    for (int mt = 0; mt < 2; ++mt)
      #pragma unroll
      for (int r = 0; r < 4; ++r) {
        const int g2 = rb + mt*16 + q*4 + r;
        float vv;
        if (isR) vv = bf2f(inBf[(size_t)g2*FCH + cc]) + bias;
        else     vv = first ? bias : (bf2f(skipB[(size_t)g2*FCH + cc]) + bias);
        acc[jj][mt][r] = vv;
      }
  }
  __syncthreads();   // the ONLY barrier: Z visible to all waves

  // ---------------- stage 2: R|S, K=256, zero barriers ----------------
  {
    s8v bbuf[2][8];
    #pragma unroll
    for (int jj = 0; jj < 8; ++jj) {
      int nt = (jj < 4) ? (w*4 + jj) : (16 + w*4 + (jj - 4));
      bbuf[0][jj] = *reinterpret_cast<const s8v*>(Bp2 + ((size_t)nt*64 + lane)*8);
    }
    for (int kc = 0; kc < 8; ++kc) {
      const int cur = kc & 1;
      if (kc < 7) {
        #pragma unroll
        for (int jj = 0; jj < 8; ++jj) {
          int nt = (jj < 4) ? (w*4 + jj) : (16 + w*4 + (jj - 4));
          bbuf[cur ^ 1][jj] = *reinterpret_cast<const s8v*>(
              Bp2 + (((size_t)(kc+1)*32 + nt)*64 + lane)*8);
        }
      }
      s8v af[2];
      #pragma unroll
      for (int mt = 0; mt < 2; ++mt)
        af[mt] = *reinterpret_cast<const s8v*>(&ldsZ[(mt*16 + i15)*264 + kc*32 + colq]);
      #pragma unroll
      for (int jj = 0; jj < 8; ++jj)
        #pragma unroll
        for (int mt = 0; mt < 2; ++mt)
          acc[jj][mt] = __builtin_amdgcn_mfma_f32_16x16x32_bf16(
              af[mt], bbuf[cur][jj], acc[jj][mt], 0,0,0);
    }
  }

  // ---------------- epilogue ----------------
  #pragma unroll
  for (int jj = 0; jj < 8; ++jj) {
    const bool isR = (jj < 4);
    const int cc = (isR ? (w*4 + jj) : (w*4 + jj - 4))*16 + i15;
    #pragma unroll
    for (int mt = 0; mt < 2; ++mt)
      #pragma unroll
      for (int r = 0; r < 4; ++r) {
        const int g2 = rb + mt*16 + q*4 + r;
        u16 hv = f2bf(acc[jj][mt][r]);
        if (isR) outBf[(size_t)g2*FCH + cc] = hv;
        else     skipB[(size_t)g2*FCH + cc] = hv;
      }
  }
}

// ---------------------------------------------------------------------------
// Final head: h=selu(skip); h=selu(h@Wd1+bd1); out=h@Wd2+bd2  -- OUT IS FP32
// ---------------------------------------------------------------------------
__global__ __launch_bounds__(256, 2) void final_kernel(
    const u16* __restrict__ skipB, const u16* __restrict__ BpD1, const u16* __restrict__ BpD2,
    const float* __restrict__ bd1, const float* __restrict__ bd2, float* __restrict__ outp)
{
  __shared__ __align__(16) u16 ldsH[64*264];
  __shared__ __align__(16) u16 ldsH2[64*72];
  const int tid = threadIdx.x;
  const int w = tid >> 6, lane = tid & 63, q = lane >> 4, i15 = lane & 15;
  const int rb = blockIdx.x * 64;
  const int sm = tid >> 2, sseg = tid & 3;

  {
    const u16* sp = skipB + (size_t)(rb + sm)*256 + sseg*64;
    u16* dr = &ldsH[sm*264 + sseg*64];
    #pragma unroll
    for (int u = 0; u < 8; ++u) {
      uint4 raw = *reinterpret_cast<const uint4*>(sp + u*8);
      u32 rr[4] = {raw.x, raw.y, raw.z, raw.w};
      uint4 o;
      u32 oo[4];
      #pragma unroll
      for (int p = 0; p < 4; ++p) {
        float e0 = seluf(bf2f((u16)(rr[p] & 0xffffu)));
        float e1 = seluf(bf2f((u16)(rr[p] >> 16)));
        oo[p] = (u32)f2bf(e0) | ((u32)f2bf(e1) << 16);
      }
      o.x = oo[0]; o.y = oo[1]; o.z = oo[2]; o.w = oo[3];
      *reinterpret_cast<uint4*>(dr + u*8) = o;
    }
  }
  __syncthreads();

  f4v a1[4];
  #pragma unroll
  for (int mt = 0; mt < 4; ++mt) a1[mt] = (f4v){0.f,0.f,0.f,0.f};
  for (int kc = 0; kc < 8; ++kc) {
    s8v b = *reinterpret_cast<const s8v*>(BpD1 + ((size_t)(kc*4 + w)*64 + lane)*8);
    #pragma unroll
    for (int mt = 0; mt < 4; ++mt) {
      s8v af = *reinterpret_cast<const s8v*>(&ldsH[(mt*16 + i15)*264 + kc*32 + q*8]);
      a1[mt] = __builtin_amdgcn_mfma_f32_16x16x32_bf16(af, b, a1[mt], 0,0,0);
    }
  }
  const float bb1 = bd1[w*16 + i15];
  #pragma unroll
  for (int mt = 0; mt < 4; ++mt)
    #pragma unroll
    for (int r = 0; r < 4; ++r)
      ldsH2[(mt*16 + q*4 + r)*72 + w*16 + i15] = f2bf(seluf(a1[mt][r] + bb1));
  __syncthreads();

  f4v a2[4];
  #pragma unroll
  for (int mt = 0; mt < 4; ++mt) a2[mt] = (f4v){0.f,0.f,0.f,0.f};
  #pragma unroll
  for (int kc = 0; kc < 2; ++kc) {
    s8v b = *reinterpret_cast<const s8v*>(BpD2 + ((size_t)(kc*4 + w)*64 + lane)*8);
    #pragma unroll
    for (int mt = 0; mt < 4; ++mt) {
      s8v af = *reinterpret_cast<const s8v*>(&ldsH2[(mt*16 + i15)*72 + kc*32 + q*8]);
      a2[mt] = __builtin_amdgcn_mfma_f32_16x16x32_bf16(af, b, a2[mt], 0,0,0);
    }
  }
  const float bb2 = bd2[w*16 + i15];
  #pragma unroll
  for (int mt = 0; mt < 4; ++mt)
    #pragma unroll
    for (int r = 0; r < 4; ++r)
      outp[(size_t)(rb + mt*16 + q*4 + r)*64 + w*16 + i15] = a2[mt][r] + bb2;  // FP32
}

// Diagnostic sentinel (should never fire; ws proven >= 84 MB).
__global__ __launch_bounds__(256) void zero_kernel(uint4* __restrict__ outp, int n16)
{
  int i = blockIdx.x*256 + threadIdx.x;
  if (i < n16) outp[i] = (uint4){0u,0u,0u,0u};
}

// ---------------------------------------------------------------------------
extern "C" void kernel_launch(void* const* d_in, const int* in_sizes, int n_in,
                              void* d_out, int out_size, void* d_ws, size_t ws_size,
                              hipStream_t stream)
{
  (void)n_in;
  const float* x   = (const float*)d_in[0];
  const float* Wc  = (const float*)d_in[1];
  const float* Wf  = (const float*)d_in[2];
  const float* Wg  = (const float*)d_in[3];
  const float* Wr  = (const float*)d_in[4];
  const float* br  = (const float*)d_in[5];
  const float* Ws  = (const float*)d_in[6];
  const float* bs  = (const float*)d_in[7];
  const float* Wd1 = (const float*)d_in[8];
  const float* bd1 = (const float*)d_in[9];
  const float* Wd2 = (const float*)d_in[10];
  const float* bd2 = (const float*)d_in[11];

  const size_t ROWS = (size_t)in_sizes[0] / 64;     // B*T = 32768
  const int gridC = (int)(ROWS / 64);               // 512  (conv0 / final)
  const int gridL = (int)(ROWS / 32);               // 1024 (layers)

  const size_t packsB = (size_t)6248 * 512 * 2;     // 6.4 MB
  const size_t bfBuf  = ROWS * 256 * 2;             // 16.78 MB
  const size_t needB = packsB + 3*bfBuf;            // 56.7 MB

  if (ws_size < needB) {
    int n16 = (out_size * 4) / 16;                  // fp32 out
    zero_kernel<<<(n16 + 255)/256, 256, 0, stream>>>((uint4*)d_out, n16);
    return;
  }

  char* ws = (char*)d_ws;
  u16* Bp1    = (u16*)ws;            ws += (size_t)4096*512*2;
  u16* Bp2    = (u16*)ws;            ws += (size_t)2048*512*2;
  u16* Bp0    = (u16*)ws;            ws += (size_t)64*512*2;
  u16* BpD1   = (u16*)ws;            ws += (size_t)32*512*2;
  u16* BpD2   = (u16*)ws;            ws += (size_t)8*512*2;
  u16* skipB  = (u16*)ws;            ws += bfBuf;
  u16* bufA   = (u16*)ws;            ws += bfBuf;
  u16* bufB   = (u16*)ws;            ws += bfBuf;

  pack_kernel<<<1562, 256, 0, stream>>>(Wc, Wf, Wg, Wr, Ws, Wd1, Wd2,
                                        Bp1, Bp2, Bp0, BpD1, BpD2);
  conv0_kernel<<<gridC, 256, 0, stream>>>(x, bufA, Bp0);
  u16* bufs[2] = {bufA, bufB};
  for (int i = 0; i < 8; ++i) {
    layer_kernel<<<gridL, 256, 0, stream>>>(
        bufs[i & 1], bufs[(i + 1) & 1], skipB,
        Bp1 + (size_t)i*262144, Bp2 + (size_t)i*131072,
        br + i*256, bs + i*256, 2 << i, (i == 0) ? 1 : 0);
  }
  final_kernel<<<gridC, 256, 0, stream>>>(skipB, BpD1, BpD2, bd1, bd2, (float*)d_out);
}

// Round 12
// 587.405 us; speedup vs baseline: 1.9672x; 1.4445x over previous
//
#include <hip/hip_runtime.h>
#include <cstdint>

typedef unsigned short u16;
typedef unsigned int u32;
typedef __attribute__((ext_vector_type(8))) short s8v;   // 8 bf16 (4 VGPRs)
typedef __attribute__((ext_vector_type(4))) float f4v;   // MFMA acc

#define FCH 256

__device__ __forceinline__ float bf2f(u16 u){ return __uint_as_float(((u32)u)<<16); }
__device__ __forceinline__ u16 f2bf(float x){
  u32 u = __float_as_uint(x);
  u += 0x7fffu + ((u>>16)&1u);
  return (u16)(u>>16);
}
__device__ __forceinline__ uint4 pack8(float4 a, float4 b){
  uint4 o;
  o.x = (u32)f2bf(a.x) | ((u32)f2bf(a.y)<<16);
  o.y = (u32)f2bf(a.z) | ((u32)f2bf(a.w)<<16);
  o.z = (u32)f2bf(b.x) | ((u32)f2bf(b.y)<<16);
  o.w = (u32)f2bf(b.z) | ((u32)f2bf(b.w)<<16);
  return o;
}
__device__ __forceinline__ float seluf(float x){
  const float sc = 1.0507009873554805f, al = 1.6732632423543772f;
  return x > 0.f ? sc*x : sc*al*(__expf(x)-1.f);
}
// XCD-stripe swizzle: blocks with bid%8==x get a contiguous tile range so
// each XCD produces/consumes one 4096-row stripe (= one batch sequence).
__device__ __forceinline__ int xcd_tile(int bid, int nT8){
  return nT8 ? ((bid & 7) * nT8 + (bid >> 3)) : bid;
}

// ---------------------------------------------------------------------------
// Weight packing (fp32 -> bf16 fragments): lane l slot j of frag (kc,nt) =
// B[kc*32 + (l>>4)*8 + j][nt*16 + (l&15)]  (16B/lane contiguous)
// ---------------------------------------------------------------------------
__global__ __launch_bounds__(256) void pack_kernel(
    const float* __restrict__ Wc, const float* __restrict__ Wf, const float* __restrict__ Wg,
    const float* __restrict__ Wr, const float* __restrict__ Ws,
    const float* __restrict__ Wd1, const float* __restrict__ Wd2,
    u16* __restrict__ Bp1, u16* __restrict__ Bp2, u16* __restrict__ Bp0,
    u16* __restrict__ BpD1, u16* __restrict__ BpD2)
{
  int gid = blockIdx.x*256 + threadIdx.x;
  int frag = gid >> 6;
  int lane = gid & 63;
  int q = lane >> 4, i15 = lane & 15;
  u16 v[8];
  u16* dst;
  if (frag < 4096) {                       // Bp1: [Wf|Wg] K=512 (tap-major)
    int layer = frag >> 9, rem = frag & 511;
    int kc = rem >> 5, nt = rem & 31;
    int n = nt*16 + i15;
    const float* W = (n < 256) ? Wf : Wg;
    int nn = (n < 256) ? n : n - 256;
    #pragma unroll
    for (int j = 0; j < 8; ++j) {
      int k = kc*32 + q*8 + j;
      int tap = k >> 8, cin = k & 255;
      v[j] = f2bf(W[((size_t)((layer*2 + tap)*256 + cin))*256 + nn]);
    }
    dst = Bp1 + (size_t)frag*512 + lane*8;
  } else if (frag < 6144) {                // Bp2: [Wr|Ws] K=256
    int f = frag - 4096;
    int layer = f >> 8, rem = f & 255;
    int kc = rem >> 5, nt = rem & 31;
    int n = nt*16 + i15;
    const float* W = (n < 256) ? Wr : Ws;
    int nn = (n < 256) ? n : n - 256;
    #pragma unroll
    for (int j = 0; j < 8; ++j) {
      int k = kc*32 + q*8 + j;
      v[j] = f2bf(W[((size_t)(layer*256 + k))*256 + nn]);
    }
    dst = Bp2 + (size_t)f*512 + lane*8;
  } else if (frag < 6208) {                // Bp0: Wc K=128
    int f = frag - 6144;
    int kc = f >> 4, nt = f & 15;
    int n = nt*16 + i15;
    #pragma unroll
    for (int j = 0; j < 8; ++j) {
      int k = kc*32 + q*8 + j;
      int tap = k >> 6, cin = k & 63;
      v[j] = f2bf(Wc[(size_t)(tap*64 + cin)*256 + n]);
    }
    dst = Bp0 + (size_t)f*512 + lane*8;
  } else if (frag < 6240) {                // BpD1: Wd1 [256,64]
    int f = frag - 6208;
    int kc = f >> 2, nt = f & 3;
    int n = nt*16 + i15;
    #pragma unroll
    for (int j = 0; j < 8; ++j) {
      int k = kc*32 + q*8 + j;
      v[j] = f2bf(Wd1[(size_t)k*64 + n]);
    }
    dst = BpD1 + (size_t)f*512 + lane*8;
  } else if (frag < 6248) {                // BpD2: Wd2 [64,64]
    int f = frag - 6240;
    int kc = f >> 2, nt = f & 3;
    int n = nt*16 + i15;
    #pragma unroll
    for (int j = 0; j < 8; ++j) {
      int k = kc*32 + q*8 + j;
      v[j] = f2bf(Wd2[(size_t)k*64 + n]);
    }
    dst = BpD2 + (size_t)f*512 + lane*8;
  } else return;
  uint4 o;
  o.x = (u32)v[0] | ((u32)v[1] << 16);
  o.y = (u32)v[2] | ((u32)v[3] << 16);
  o.z = (u32)v[4] | ((u32)v[5] << 16);
  o.w = (u32)v[6] | ((u32)v[7] << 16);
  *reinterpret_cast<uint4*>(dst) = o;
}

// ---------------------------------------------------------------------------
// Initial causal conv (dilation 1, no bias): out0 = [x[t-1]|x[t]] @ cat(Wc)
// ---------------------------------------------------------------------------
__global__ __launch_bounds__(256, 2) void conv0_kernel(
    const float* __restrict__ x, u16* __restrict__ outBf,
    const u16* __restrict__ Bp0, int nT8)
{
  __shared__ __align__(16) u16 ldsA[2][2048];
  const int tid = threadIdx.x;
  const int w = tid >> 6, lane = tid & 63, q = lane >> 4, i15 = lane & 15;
  const int rb = xcd_tile(blockIdx.x, nT8) * 64;
  const int sm = tid >> 2, sg = tid & 3;
  const int grow = rb + sm;
  const int tpos = grow & 4095;
  const int sunit = ((sm >> 4)*64 + sg*16 + ((sm & 15) ^ (sg << 1))) * 8;
  const int runit = (q*16 + (i15 ^ (q << 1))) * 8;

  f4v acc[4][4];
  #pragma unroll
  for (int jj = 0; jj < 4; ++jj)
    #pragma unroll
    for (int mt = 0; mt < 4; ++mt)
      acc[jj][mt] = (f4v){0.f,0.f,0.f,0.f};

  float4 f0 = {0.f,0.f,0.f,0.f}, f1 = {0.f,0.f,0.f,0.f};
  if (tpos >= 1) {
    const float* px = x + (size_t)(grow-1)*64 + sg*8;
    f0 = *reinterpret_cast<const float4*>(px);
    f1 = *reinterpret_cast<const float4*>(px + 4);
  }
  *reinterpret_cast<uint4*>(&ldsA[0][sunit]) = pack8(f0, f1);
  s8v bcur[4], bnxt[4];
  #pragma unroll
  for (int jj = 0; jj < 4; ++jj)
    bcur[jj] = *reinterpret_cast<const s8v*>(Bp0 + ((size_t)(w + 4*jj)*64 + lane)*8);
  __syncthreads();

  for (int kc = 0; kc < 4; ++kc) {
    const int cur = kc & 1;
    uint4 an = {0u,0u,0u,0u};
    if (kc < 3) {
      int kg = (kc+1)*32 + sg*8;
      int tap = kg >> 6, col = kg & 63;
      float4 g0 = {0.f,0.f,0.f,0.f}, g1 = {0.f,0.f,0.f,0.f};
      if (tap) {
        const float* px = x + (size_t)grow*64 + col;
        g0 = *reinterpret_cast<const float4*>(px);
        g1 = *reinterpret_cast<const float4*>(px + 4);
      } else if (tpos >= 1) {
        const float* px = x + (size_t)(grow-1)*64 + col;
        g0 = *reinterpret_cast<const float4*>(px);
        g1 = *reinterpret_cast<const float4*>(px + 4);
      }
      an = pack8(g0, g1);
      #pragma unroll
      for (int jj = 0; jj < 4; ++jj)
        bnxt[jj] = *reinterpret_cast<const s8v*>(Bp0 + (((size_t)(kc+1)*16 + (w + 4*jj))*64 + lane)*8);
    }
    s8v af[4];
    #pragma unroll
    for (int mt = 0; mt < 4; ++mt)
      af[mt] = *reinterpret_cast<const s8v*>(&ldsA[cur][mt*512 + runit]);
    #pragma unroll
    for (int jj = 0; jj < 4; ++jj)
      #pragma unroll
      for (int mt = 0; mt < 4; ++mt)
        acc[jj][mt] = __builtin_amdgcn_mfma_f32_16x16x32_bf16(af[mt], bcur[jj], acc[jj][mt], 0,0,0);
    if (kc < 3) {
      *reinterpret_cast<uint4*>(&ldsA[cur ^ 1][sunit]) = an;
      #pragma unroll
      for (int jj = 0; jj < 4; ++jj) bcur[jj] = bnxt[jj];
    }
    __syncthreads();
  }

  #pragma unroll
  for (int jj = 0; jj < 4; ++jj) {
    const int cc = (w + 4*jj)*16 + i15;
    #pragma unroll
    for (int mt = 0; mt < 4; ++mt)
      #pragma unroll
      for (int r = 0; r < 4; ++r) {
        const int g2 = rb + mt*16 + q*4 + r;
        outBf[(size_t)g2*FCH + cc] = f2bf(acc[jj][mt][r]);
      }
  }
}

// ---------------------------------------------------------------------------
// One WaveNet residual layer (r9 structure + XCD-stripe swizzle).
// M=32 rows/block (1024 blocks), bf16 residual ping-pong.
//   stage1: F|G = [in[t-d]|in[t]] @ (Wf|Wg)   (K=512, N=512)
//   Z = tanh(F)*sigmoid(G) -> LDS (row-major, pad 264)
//   stage2: R|S = Z @ (Wr|Ws); out = in + R + br; skip (=|+=) S + bs
// ---------------------------------------------------------------------------
__global__ __launch_bounds__(256, 3) void layer_kernel(
    const u16* __restrict__ inBf, u16* __restrict__ outBf,
    u16* __restrict__ skipB,
    const u16* __restrict__ Bp1, const u16* __restrict__ Bp2,
    const float* __restrict__ br, const float* __restrict__ bs,
    int dil, int first, int nT8)
{
  __shared__ __align__(16) u16 ldsA[2][32*40];   // 2 x 2.5 KB
  __shared__ __align__(16) u16 ldsZ[32*264];     // 16.9 KB
  const int tid = threadIdx.x;
  const int w = tid >> 6, lane = tid & 63, q = lane >> 4, i15 = lane & 15;
  const int rb = xcd_tile(blockIdx.x, nT8) * 32;
  const int sm = tid >> 3, sg = tid & 7;         // staging: row sm, 8B group sg
  const int grow = rb + sm;
  const int tpos = grow & 4095;

  f4v acc[8][2];   // [jj: nt=w+4*jj][mt]
  #pragma unroll
  for (int jj = 0; jj < 8; ++jj)
    #pragma unroll
    for (int mt = 0; mt < 2; ++mt)
      acc[jj][mt] = (f4v){0.f,0.f,0.f,0.f};

  // ---------------- stage 1 ----------------
  {
    uint2 a0 = {0u,0u};
    if (tpos >= dil)   // chunk0 = tap0 (k<256): row t-d
      a0 = *reinterpret_cast<const uint2*>(inBf + (size_t)(grow - dil)*FCH + sg*4);
    *reinterpret_cast<uint2*>(&ldsA[0][sm*40 + sg*4]) = a0;
    s8v bcur[8], bnxt[8];
    #pragma unroll
    for (int jj = 0; jj < 8; ++jj)
      bcur[jj] = *reinterpret_cast<const s8v*>(Bp1 + ((size_t)(w + 4*jj)*64 + lane)*8);
    __syncthreads();

    for (int kc = 0; kc < 16; ++kc) {
      const int cur = kc & 1;
      uint2 an = {0u,0u};
      if (kc < 15) {
        int kg = (kc+1)*32 + sg*4;
        int tap = kg >> 8, col = kg & 255;
        if (tap) an = *reinterpret_cast<const uint2*>(inBf + (size_t)grow*FCH + col);
        else if (tpos >= dil) an = *reinterpret_cast<const uint2*>(inBf + (size_t)(grow - dil)*FCH + col);
        #pragma unroll
        for (int jj = 0; jj < 8; ++jj)
          bnxt[jj] = *reinterpret_cast<const s8v*>(Bp1 + (((size_t)(kc+1)*32 + (w + 4*jj))*64 + lane)*8);
      }
      s8v af[2];
      #pragma unroll
      for (int mt = 0; mt < 2; ++mt)
        af[mt] = *reinterpret_cast<const s8v*>(&ldsA[cur][(mt*16 + i15)*40 + q*8]);
      #pragma unroll
      for (int jj = 0; jj < 8; ++jj)
        #pragma unroll
        for (int mt = 0; mt < 2; ++mt)
          acc[jj][mt] = __builtin_amdgcn_mfma_f32_16x16x32_bf16(af[mt], bcur[jj], acc[jj][mt], 0,0,0);
      if (kc < 15) {
        *reinterpret_cast<uint2*>(&ldsA[cur ^ 1][sm*40 + sg*4]) = an;
        #pragma unroll
        for (int jj = 0; jj < 8; ++jj) bcur[jj] = bnxt[jj];
      }
      __syncthreads();
    }
  }

  // ---------------- activation: Z -> LDS (C-layout -> row-major) ----------------
  #pragma unroll
  for (int jj = 0; jj < 4; ++jj) {
    const int colb = (w + 4*jj)*16 + i15;
    #pragma unroll
    for (int mt = 0; mt < 2; ++mt)
      #pragma unroll
      for (int r = 0; r < 4; ++r) {
        float f = acc[jj][mt][r];
        float g = acc[jj+4][mt][r];
        float z = (1.f - 2.f/(__expf(2.f*f) + 1.f)) * (1.f/(1.f + __expf(-g)));
        ldsZ[(mt*16 + q*4 + r)*264 + colb] = f2bf(z);
      }
  }
  __syncthreads();

  // ---------------- init stage-2 acc: residual (bf16) / skip / bias ----------------
  #pragma unroll
  for (int jj = 0; jj < 8; ++jj) {
    const int nt = w + 4*jj;
    const bool isR = (jj < 4);
    const int cc = (isR ? nt*16 : (nt-16)*16) + i15;
    const float bias = isR ? br[cc] : bs[cc];
    #pragma unroll
    for (int mt = 0; mt < 2; ++mt)
      #pragma unroll
      for (int r = 0; r < 4; ++r) {
        const int g2 = rb + mt*16 + q*4 + r;
        float vv;
        if (isR) vv = bf2f(inBf[(size_t)g2*FCH + cc]) + bias;
        else     vv = first ? bias : (bf2f(skipB[(size_t)g2*FCH + cc]) + bias);
        acc[jj][mt][r] = vv;
      }
  }

  // ---------------- stage 2 ----------------
  {
    s8v b2c[8], b2n[8];
    #pragma unroll
    for (int jj = 0; jj < 8; ++jj)
      b2c[jj] = *reinterpret_cast<const s8v*>(Bp2 + ((size_t)(w + 4*jj)*64 + lane)*8);
    for (int kc = 0; kc < 8; ++kc) {
      if (kc < 7) {
        #pragma unroll
        for (int jj = 0; jj < 8; ++jj)
          b2n[jj] = *reinterpret_cast<const s8v*>(Bp2 + (((size_t)(kc+1)*32 + (w + 4*jj))*64 + lane)*8);
      }
      s8v af[2];
      #pragma unroll
      for (int mt = 0; mt < 2; ++mt)
        af[mt] = *reinterpret_cast<const s8v*>(&ldsZ[(mt*16 + i15)*264 + kc*32 + q*8]);
      #pragma unroll
      for (int jj = 0; jj < 8; ++jj)
        #pragma unroll
        for (int mt = 0; mt < 2; ++mt)
          acc[jj][mt] = __builtin_amdgcn_mfma_f32_16x16x32_bf16(af[mt], b2c[jj], acc[jj][mt], 0,0,0);
      if (kc < 7) {
        #pragma unroll
        for (int jj = 0; jj < 8; ++jj) b2c[jj] = b2n[jj];
      }
    }
  }

  // ---------------- epilogue (bf16 out + skip) ----------------
  #pragma unroll
  for (int jj = 0; jj < 8; ++jj) {
    const int nt = w + 4*jj;
    const bool isR = (jj < 4);
    const int cc = (isR ? nt*16 : (nt-16)*16) + i15;
    #pragma unroll
    for (int mt = 0; mt < 2; ++mt)
      #pragma unroll
      for (int r = 0; r < 4; ++r) {
        const int g2 = rb + mt*16 + q*4 + r;
        u16 hv = f2bf(acc[jj][mt][r]);
        if (isR) outBf[(size_t)g2*FCH + cc] = hv;
        else     skipB[(size_t)g2*FCH + cc] = hv;
      }
  }
}

// ---------------------------------------------------------------------------
// Final head: h=selu(skip); h=selu(h@Wd1+bd1); out=h@Wd2+bd2  -- OUT IS FP32
// ---------------------------------------------------------------------------
__global__ __launch_bounds__(256, 2) void final_kernel(
    const u16* __restrict__ skipB, const u16* __restrict__ BpD1, const u16* __restrict__ BpD2,
    const float* __restrict__ bd1, const float* __restrict__ bd2, float* __restrict__ outp,
    int nT8)
{
  __shared__ __align__(16) u16 ldsH[64*264];
  __shared__ __align__(16) u16 ldsH2[64*72];
  const int tid = threadIdx.x;
  const int w = tid >> 6, lane = tid & 63, q = lane >> 4, i15 = lane & 15;
  const int rb = xcd_tile(blockIdx.x, nT8) * 64;
  const int sm = tid >> 2, sseg = tid & 3;

  {
    const u16* sp = skipB + (size_t)(rb + sm)*256 + sseg*64;
    u16* dr = &ldsH[sm*264 + sseg*64];
    #pragma unroll
    for (int u = 0; u < 8; ++u) {
      uint4 raw = *reinterpret_cast<const uint4*>(sp + u*8);
      u32 rr[4] = {raw.x, raw.y, raw.z, raw.w};
      uint4 o;
      u32 oo[4];
      #pragma unroll
      for (int p = 0; p < 4; ++p) {
        float e0 = seluf(bf2f((u16)(rr[p] & 0xffffu)));
        float e1 = seluf(bf2f((u16)(rr[p] >> 16)));
        oo[p] = (u32)f2bf(e0) | ((u32)f2bf(e1) << 16);
      }
      o.x = oo[0]; o.y = oo[1]; o.z = oo[2]; o.w = oo[3];
      *reinterpret_cast<uint4*>(dr + u*8) = o;
    }
  }
  __syncthreads();

  f4v a1[4];
  #pragma unroll
  for (int mt = 0; mt < 4; ++mt) a1[mt] = (f4v){0.f,0.f,0.f,0.f};
  for (int kc = 0; kc < 8; ++kc) {
    s8v b = *reinterpret_cast<const s8v*>(BpD1 + ((size_t)(kc*4 + w)*64 + lane)*8);
    #pragma unroll
    for (int mt = 0; mt < 4; ++mt) {
      s8v af = *reinterpret_cast<const s8v*>(&ldsH[(mt*16 + i15)*264 + kc*32 + q*8]);
      a1[mt] = __builtin_amdgcn_mfma_f32_16x16x32_bf16(af, b, a1[mt], 0,0,0);
    }
  }
  const float bb1 = bd1[w*16 + i15];
  #pragma unroll
  for (int mt = 0; mt < 4; ++mt)
    #pragma unroll
    for (int r = 0; r < 4; ++r)
      ldsH2[(mt*16 + q*4 + r)*72 + w*16 + i15] = f2bf(seluf(a1[mt][r] + bb1));
  __syncthreads();

  f4v a2[4];
  #pragma unroll
  for (int mt = 0; mt < 4; ++mt) a2[mt] = (f4v){0.f,0.f,0.f,0.f};
  #pragma unroll
  for (int kc = 0; kc < 2; ++kc) {
    s8v b = *reinterpret_cast<const s8v*>(BpD2 + ((size_t)(kc*4 + w)*64 + lane)*8);
    #pragma unroll
    for (int mt = 0; mt < 4; ++mt) {
      s8v af = *reinterpret_cast<const s8v*>(&ldsH2[(mt*16 + i15)*72 + kc*32 + q*8]);
      a2[mt] = __builtin_amdgcn_mfma_f32_16x16x32_bf16(af, b, a2[mt], 0,0,0);
    }
  }
  const float bb2 = bd2[w*16 + i15];
  #pragma unroll
  for (int mt = 0; mt < 4; ++mt)
    #pragma unroll
    for (int r = 0; r < 4; ++r)
      outp[(size_t)(rb + mt*16 + q*4 + r)*64 + w*16 + i15] = a2[mt][r] + bb2;  // FP32
}

// Diagnostic sentinel (should never fire; ws proven >= 84 MB).
__global__ __launch_bounds__(256) void zero_kernel(uint4* __restrict__ outp, int n16)
{
  int i = blockIdx.x*256 + threadIdx.x;
  if (i < n16) outp[i] = (uint4){0u,0u,0u,0u};
}

// ---------------------------------------------------------------------------
extern "C" void kernel_launch(void* const* d_in, const int* in_sizes, int n_in,
                              void* d_out, int out_size, void* d_ws, size_t ws_size,
                              hipStream_t stream)
{
  (void)n_in;
  const float* x   = (const float*)d_in[0];
  const float* Wc  = (const float*)d_in[1];
  const float* Wf  = (const float*)d_in[2];
  const float* Wg  = (const float*)d_in[3];
  const float* Wr  = (const float*)d_in[4];
  const float* br  = (const float*)d_in[5];
  const float* Ws  = (const float*)d_in[6];
  const float* bs  = (const float*)d_in[7];
  const float* Wd1 = (const float*)d_in[8];
  const float* bd1 = (const float*)d_in[9];
  const float* Wd2 = (const float*)d_in[10];
  const float* bd2 = (const float*)d_in[11];

  const size_t ROWS = (size_t)in_sizes[0] / 64;     // B*T = 32768
  const int gridC = (int)(ROWS / 64);               // 512  (conv0 / final)
  const int gridL = (int)(ROWS / 32);               // 1024 (layers)
  const int nT8C = (gridC % 8 == 0) ? gridC / 8 : 0;
  const int nT8L = (gridL % 8 == 0) ? gridL / 8 : 0;

  const size_t packsB = (size_t)6248 * 512 * 2;     // 6.4 MB
  const size_t bfBuf  = ROWS * 256 * 2;             // 16.78 MB
  const size_t needB = packsB + 3*bfBuf;            // 56.7 MB

  if (ws_size < needB) {
    int n16 = (out_size * 4) / 16;                  // fp32 out
    zero_kernel<<<(n16 + 255)/256, 256, 0, stream>>>((uint4*)d_out, n16);
    return;
  }

  char* ws = (char*)d_ws;
  u16* Bp1    = (u16*)ws;            ws += (size_t)4096*512*2;
  u16* Bp2    = (u16*)ws;            ws += (size_t)2048*512*2;
  u16* Bp0    = (u16*)ws;            ws += (size_t)64*512*2;
  u16* BpD1   = (u16*)ws;            ws += (size_t)32*512*2;
  u16* BpD2   = (u16*)ws;            ws += (size_t)8*512*2;
  u16* skipB  = (u16*)ws;            ws += bfBuf;
  u16* bufA   = (u16*)ws;            ws += bfBuf;
  u16* bufB   = (u16*)ws;            ws += bfBuf;

  pack_kernel<<<1562, 256, 0, stream>>>(Wc, Wf, Wg, Wr, Ws, Wd1, Wd2,
                                        Bp1, Bp2, Bp0, BpD1, BpD2);
  conv0_kernel<<<gridC, 256, 0, stream>>>(x, bufA, Bp0, nT8C);
  u16* bufs[2] = {bufA, bufB};
  for (int i = 0; i < 8; ++i) {
    layer_kernel<<<gridL, 256, 0, stream>>>(
        bufs[i & 1], bufs[(i + 1) & 1], skipB,
        Bp1 + (size_t)i*262144, Bp2 + (size_t)i*131072,
        br + i*256, bs + i*256, 2 << i, (i == 0) ? 1 : 0, nT8L);
  }
  final_kernel<<<gridC, 256, 0, stream>>>(skipB, BpD1, BpD2, bd1, bd2,
                                          (float*)d_out, nT8C);
}